// Round 2
// baseline (159.621 us; speedup 1.0000x reference)
//
#include <hip/hip_runtime.h>

#define TMAX 64

__global__ __launch_bounds__(256) void snn_fused(
    const float* __restrict__ x,       // [B,1,10,10]
    const float* __restrict__ conv_w,  // [2,1,4,4]
    const float* __restrict__ conv_b,  // [2]
    const float* __restrict__ fc_w,    // [10,72]
    const float* __restrict__ fc_b,    // [10]
    const int*   __restrict__ nsteps,  // scalar
    float*       __restrict__ out,     // [B,10]
    int B)
{
    __shared__ double d_F[TMAX];       // F(m) = 0.9^m - 0.8^m  (double)
    __shared__ float  s_r[TMAX];       // r_s = G(T-1-s)
    __shared__ float  s_tab[8][256];   // byte tables: sum of r over set bits
    __shared__ float  s_fcw[720];
    __shared__ float  s_fcb[16];
    __shared__ float  s_cb;            // C_b = sum_{m<T} F(m)

    const int tid = threadIdx.x;
    int T = nsteps[0];
    if (T > TMAX) T = TMAX;
    if (T < 0) T = 0;

    // --- setup: F(m) in double ---
    if (tid < TMAX) {
        double p9 = 1.0, p8 = 1.0;
        for (int k = 0; k < tid; ++k) { p9 *= 0.9; p8 *= 0.8; }
        d_F[tid] = p9 - p8;
    }
    for (int idx = tid; idx < 720; idx += 256) s_fcw[idx] = fc_w[idx];
    if (tid < 10) s_fcb[tid] = fc_b[tid];
    __syncthreads();

    // --- r_s = G(T-1-s), double accumulate ---
    if (tid < TMAX) {
        double r = 0.0;
        if (tid < T) {
            const int n = T - 1 - tid;
            for (int u = 0; u <= n; ++u) r += d_F[n - u] * d_F[u];
        }
        s_r[tid] = (float)r;
    }
    if (tid == 0) {
        double cb = 0.0;
        for (int m = 0; m < T; ++m) cb += d_F[m];
        s_cb = (float)cb;
    }
    __syncthreads();

    // --- byte lookup tables (from float r; linear path, rounding harmless) ---
    {
        const int v8 = tid; // 0..255
        #pragma unroll
        for (int k = 0; k < 8; ++k) {
            float ssum = 0.f;
            #pragma unroll
            for (int bb = 0; bb < 8; ++bb)
                if ((v8 >> bb) & 1) ssum += s_r[k * 8 + bb];
            s_tab[k][v8] = ssum;
        }
    }
    __syncthreads();

    const float cbsum = s_cb;

    const int gt = blockIdx.x * 256 + tid;
    const int b = gt >> 1;
    const int c = gt & 1;
    if (b >= B) return;

    const float* xb = x + b * 100;

    // raw conv weights (no pre-scaling — must match reference products exactly)
    float wc[16];
    {
        const float4* wq = reinterpret_cast<const float4*>(conv_w + c * 16);
        #pragma unroll
        for (int k = 0; k < 4; ++k) {
            float4 t = wq[k];
            wc[4*k+0] = t.x; wc[4*k+1] = t.y; wc[4*k+2] = t.z; wc[4*k+3] = t.w;
        }
    }
    const float cbias = conv_b[c];

    // rolling 4-row window of x
    float xr[4][10];
    #pragma unroll
    for (int rr = 0; rr < 3; ++rr) {
        const float2* q = reinterpret_cast<const float2*>(xb + rr * 10);
        #pragma unroll
        for (int k = 0; k < 5; ++k) { float2 t = q[k]; xr[rr][2*k] = t.x; xr[rr][2*k+1] = t.y; }
    }

    float outacc[10];
    #pragma unroll
    for (int o = 0; o < 10; ++o) outacc[o] = 0.f;

    unsigned int plo[7], phi[7];   // previous LIF row spike masks

    const int tlo = T < 32 ? T : 32;
    const int thi = T > 32 ? (T - 32) : 0;

    #pragma unroll
    for (int y = 0; y < 7; ++y) {
        // load x row y+3
        {
            const int rr = y + 3;
            const float2* q = reinterpret_cast<const float2*>(xb + rr * 10);
            #pragma unroll
            for (int k = 0; k < 5; ++k) { float2 t = q[k]; xr[rr & 3][2*k] = t.x; xr[rr & 3][2*k+1] = t.y; }
        }
        // conv row: sequential mul/add in (ky,kx) order, then + bias (reference order)
        float gg[7];
        #pragma unroll
        for (int xx = 0; xx < 7; ++xx) {
            float a = 0.f;
            #pragma unroll
            for (int ky = 0; ky < 4; ++ky) {
                #pragma unroll
                for (int kx = 0; kx < 4; ++kx)
                    a = __fadd_rn(a, __fmul_rn(wc[ky*4+kx], xr[(y+ky)&3][xx+kx]));
            }
            gg[xx] = __fadd_rn(a, cbias);
        }

        // LIF sim — EXACT reference fp32 arithmetic:
        //   v_dec = v + 0.1f*((0-v)+i);  i_dec = i - 0.2f*i
        //   z = v_dec > 1;  v = z?0:v_dec;  i = i_dec + g
        float v[7], ii[7];
        unsigned int mlo[7], mhi[7];
        #pragma unroll
        for (int xx = 0; xx < 7; ++xx) { v[xx] = 0.f; ii[xx] = 0.f; mlo[xx] = 0u; mhi[xx] = 0u; }

        for (int t = 0; t < tlo; ++t) {
            const unsigned int bit = 1u << t;
            #pragma unroll
            for (int xx = 0; xx < 7; ++xx) {
                const float imv  = __fsub_rn(ii[xx], v[xx]);
                const float vdec = __fadd_rn(v[xx], __fmul_rn(0.1f, imv));
                const float idec = __fsub_rn(ii[xx], __fmul_rn(0.2f, ii[xx]));
                const bool  sp   = vdec > 1.0f;
                v[xx]  = sp ? 0.f : vdec;
                ii[xx] = __fadd_rn(idec, gg[xx]);
                if (sp) mlo[xx] |= bit;
            }
        }
        for (int t = 0; t < thi; ++t) {
            const unsigned int bit = 1u << t;
            #pragma unroll
            for (int xx = 0; xx < 7; ++xx) {
                const float imv  = __fsub_rn(ii[xx], v[xx]);
                const float vdec = __fadd_rn(v[xx], __fmul_rn(0.1f, imv));
                const float idec = __fsub_rn(ii[xx], __fmul_rn(0.2f, ii[xx]));
                const bool  sp   = vdec > 1.0f;
                v[xx]  = sp ? 0.f : vdec;
                ii[xx] = __fadd_rn(idec, gg[xx]);
                if (sp) mhi[xx] |= bit;
            }
        }

        // pool (OR of 4 neighbor masks) + temporal weighting + FC accumulate
        if (y > 0) {
            const int jbase = c * 36 + (y - 1) * 6;
            #pragma unroll
            for (int px = 0; px < 6; ++px) {
                const unsigned int pl = plo[px] | plo[px+1] | mlo[px] | mlo[px+1];
                const unsigned int ph = phi[px] | phi[px+1] | mhi[px] | mhi[px+1];
                float a = s_tab[0][pl & 255] + s_tab[1][(pl >> 8) & 255]
                        + s_tab[2][(pl >> 16) & 255] + s_tab[3][pl >> 24]
                        + s_tab[4][ph & 255] + s_tab[5][(ph >> 8) & 255]
                        + s_tab[6][(ph >> 16) & 255] + s_tab[7][ph >> 24];
                const int j = jbase + px;
                #pragma unroll
                for (int o = 0; o < 10; ++o)
                    outacc[o] = fmaf(s_fcw[o * 72 + j], a, outacc[o]);
            }
        }
        #pragma unroll
        for (int xx = 0; xx < 7; ++xx) { plo[xx] = mlo[xx]; phi[xx] = mhi[xx]; }
    }

    // reduce the two channel-threads, add bias response, store
    #pragma unroll
    for (int o = 0; o < 10; ++o) {
        float tot = outacc[o] + __shfl_xor(outacc[o], 1);
        tot = fmaf(cbsum, s_fcb[o], tot);
        if (c == 0) out[b * 10 + o] = tot;
    }
}

extern "C" void kernel_launch(void* const* d_in, const int* in_sizes, int n_in,
                              void* d_out, int out_size, void* d_ws, size_t ws_size,
                              hipStream_t stream) {
    const float* x      = (const float*)d_in[0];
    const float* conv_w = (const float*)d_in[1];
    const float* conv_b = (const float*)d_in[2];
    const float* fc_w   = (const float*)d_in[3];
    const float* fc_b   = (const float*)d_in[4];
    const int*   nsteps = (const int*)d_in[5];
    float* outp = (float*)d_out;

    const int B = in_sizes[0] / 100;
    const int total = 2 * B;
    const int block = 256;
    const int grid = (total + block - 1) / block;
    snn_fused<<<grid, block, 0, stream>>>(x, conv_w, conv_b, fc_w, fc_b, nsteps, outp, B);
}